// Round 1
// baseline (502.011 us; speedup 1.0000x reference)
//
#include <hip/hip_runtime.h>

#define IN_C 512
#define OUT_C 512
#define BATCH 16
#define NPX 4096   // 64*64

using bf16x8 = __attribute__((ext_vector_type(8))) __bf16;
using f32x4  = __attribute__((ext_vector_type(4))) float;

static constexpr float kConvScale = 0.014731391274719739f; // 1/sqrt(512*9)
static constexpr float kModScale  = 0.04419417382415922f;  // 1/sqrt(512)
static constexpr float kEps       = 1e-8f;

#define WT_TILE_BYTES (9 * 128 * 64)   // 73728 B per (ics, ot) weight tile

// ---------- 1) s[b][ic] = style[b,:] . mod_weight[ic,:] * MOD_SCALE + mod_bias[ic]
__global__ void style_k(const float* __restrict__ style, const float* __restrict__ mw,
                        const float* __restrict__ mb, float* __restrict__ s) {
  __shared__ float st[IN_C];
  const int b = blockIdx.x, t = threadIdx.x;   // 512 threads
  st[t] = style[b * IN_C + t];
  __syncthreads();
  const float4* row = (const float4*)(mw + (size_t)t * IN_C);
  float acc = 0.f;
  #pragma unroll 4
  for (int i = 0; i < IN_C / 4; i++) {
    float4 v = row[i];
    float4 u = *(const float4*)(st + i * 4);
    acc += v.x * u.x + v.y * u.y + v.z * u.z + v.w * u.w;
  }
  s[b * IN_C + t] = acc * kModScale + mb[t];
}

// ---------- 2) wsq[oc][ic] = sum_tap w^2 ; wsw = bf16 weights, tile-major + XOR-swizzled
__global__ void wprep_k(const float* __restrict__ w, float* __restrict__ wsq,
                        char* __restrict__ wsw) {
  const int idx = blockIdx.x * 256 + threadIdx.x;  // 262144 total
  const int ic = idx & (IN_C - 1), oc = idx >> 9;
  const int ot = oc >> 7, ocl = oc & 127, ics = ic >> 5, icl = ic & 31;
  char* tile = wsw + (size_t)(ics * 4 + ot) * WT_TILE_BYTES;
  const float* p = w + (size_t)(oc * IN_C + ic) * 9;
  float q = 0.f;
  #pragma unroll
  for (int t = 0; t < 9; t++) {
    float v = p[t];
    q += v * v;
    int B = ((t * 128 + ocl) << 6) + icl * 2;
    int Bsw = B ^ (((B >> 7) & 7) << 4);
    *(__bf16*)(tile + Bsw) = (__bf16)v;
  }
  wsq[oc * IN_C + ic] = q;
}

// ---------- 3) dscale[b][oc] = CONV_SCALE * rsqrt(CONV_SCALE^2 * sum_ic s^2*wsq + eps)
__global__ void demod_k(const float* __restrict__ s, const float* __restrict__ wsq,
                        float* __restrict__ dsc) {
  __shared__ float s2[IN_C];
  const int b = blockIdx.x, t = threadIdx.x;   // 512 threads
  float sv = s[b * IN_C + t];
  s2[t] = sv * sv;
  __syncthreads();
  const float4* row = (const float4*)(wsq + (size_t)t * IN_C);
  float acc = 0.f;
  #pragma unroll 4
  for (int i = 0; i < IN_C / 4; i++) {
    float4 v = row[i];
    float4 u = *(const float4*)(s2 + i * 4);
    acc += v.x * u.x + v.y * u.y + v.z * u.z + v.w * u.w;
  }
  dsc[b * OUT_C + t] = kConvScale * rsqrtf(kConvScale * kConvScale * acc + kEps);
}

// ---------- 4) xmod[b][p][ic] = bf16(x[b][ic][p] * s[b][ic])   (NCHW -> NHWC transpose)
__global__ void modx_k(const float* __restrict__ x, const float* __restrict__ s,
                       __bf16* __restrict__ xm) {
  __shared__ __bf16 tile[64][73];
  const int t = threadIdx.x;                   // 256 threads
  const int bid = blockIdx.x;                  // 16 * 8 * 64
  const int ict = bid & 7, pt = (bid >> 3) & 63, b = bid >> 9;
  const int ic0 = ict * 64, p0 = pt * 64;
  #pragma unroll
  for (int it = 0; it < 16; it++) {
    int idx = it * 256 + t;
    int pl = idx & 63, icl = idx >> 6;
    int ic = ic0 + icl;
    float v = x[((size_t)b * IN_C + ic) * NPX + p0 + pl] * s[b * IN_C + ic];
    tile[icl][pl] = (__bf16)v;
  }
  __syncthreads();
  #pragma unroll
  for (int it = 0; it < 2; it++) {
    int idx = it * 256 + t;
    int icb = idx & 7, pl = idx >> 3;
    alignas(16) __bf16 tmp[8];
    #pragma unroll
    for (int j = 0; j < 8; j++) tmp[j] = tile[icb * 8 + j][pl];
    *(uint4*)(xm + ((size_t)b * NPX + p0 + pl) * IN_C + ic0 + icb * 8) = *(const uint4*)tmp;
  }
}

// ---------- 5) conv: 512 thr (8 waves), tile 128 oc x 512 px.
// NEW (this round): rolling 3-group weight prefetch with COUNTED vmcnt (T3+T4) —
// the old schedule drained all 9 taps' glds (73.7 KB from L2) to vmcnt(0) between
// two barriers every step: ~5-7K serialized cycles/step (MfmaUtil 56.6%).
// Now taps are grouped {0-2},{3-5},{6-8}; group g of step s+1 is prefetched while
// group g+1 of step s computes; barriers wait vmcnt(3/8/3), never 0 in the loop.
// xs is double-buffered in 32-ic halves ([10][66][64ic] rows, 128 B/row-slot) with a
// chunk-permutation swizzle pos=(chunk + sigma((slot-1)&7))&7, sigma(u)=4(u&1)+((u>>1)&3):
// 2-way (minimum) on 16-slot b128 reads AND 2-way on 4-slot x 4-chunk b128 writes.
// T5: s_setprio(1) around each MFMA cluster (group schedule gives wave role diversity).
// LDS: 84480 (xs) + 73728 (w) = 158208 B -> still 1 block/CU, 8 waves.

#define SGB __builtin_amdgcn_sched_group_barrier
#define SGB_MIX() { SGB(0x100, 3, 0); SGB(0x8, 8, 0); SGB(0x100, 3, 0); SGB(0x8, 8, 0); \
                    SGB(0x100, 3, 0); SGB(0x8, 8, 0); SGB(0x100, 3, 0); SGB(0x8, 8, 0); }
#define SGB_MFMA() { SGB(0x8, 8, 0); SGB(0x8, 8, 0); SGB(0x8, 8, 0); SGB(0x8, 8, 0); }

#define WAITV(N) asm volatile("s_waitcnt vmcnt(" #N ")" ::: "memory")
#define WAITL()  asm volatile("s_waitcnt lgkmcnt(0)" ::: "memory")
#define SBAR()   { __builtin_amdgcn_sched_barrier(0); __builtin_amdgcn_s_barrier(); \
                   __builtin_amdgcn_sched_barrier(0); }
#define PRIO1()  __builtin_amdgcn_s_setprio(1)
#define PRIO0()  __builtin_amdgcn_s_setprio(0)

__device__ __forceinline__ int swz8(int u) { return 4 * (u & 1) + ((u >> 1) & 3); }

__global__ __launch_bounds__(512, 2)
void conv_k(const __bf16* __restrict__ xm, const char* __restrict__ wsw,
            const float* __restrict__ dsc, float* __restrict__ out) {
  // xs rows: r in 0..9 (h0-1..h0+8), slots 0..65 (halo cols 0,65), 64 ic (2 halves),
  // 128 B per (r,slot) row, swizzled 16B chunks. Flat char addressing.
  __shared__ __align__(16) char xsb_s[10 * 66 * 128];   // 84480 B
  __shared__ uint4 wsb4[WT_TILE_BYTES / 16];            // 73728 B (linear glds dest)
  char* xsb = xsb_s;
  char* wsb = (char*)wsb4;

  const int tid = threadIdx.x;
  const int lane = tid & 63;
  const int wv = tid >> 6;
  const int wm = wv >> 2, wn = wv & 3;       // 2 oc-halves x 4 px-quarters
  const int l15 = lane & 15, kb8 = lane >> 4;
  const int l7 = l15 & 7;
  const int bid = blockIdx.x;
  const int pt = bid & 7, ot = (bid >> 3) & 3, b = bid >> 5;
  const int h0 = pt * 8, oc0 = ot * 128;

  // input staging geometry: thread -> (ckb, c, r-parity)
  const int s_ckb = tid & 3, s_c = (tid >> 2) & 63, s_rb = tid >> 8;
  const __bf16* xbase = xm + (size_t)b * NPX * IN_C + s_c * IN_C + s_ckb * 8;

  // swizzle positions (byte offsets within the 128 B row):
  // read: dx in {0,1,2}: u=(l7+dx+7)&7; half-1 variant = XOR 64 (adding 4 mod 8 == ^4)
  const int rp_0 = ((kb8 + swz8((l7 + 7) & 7)) & 7) * 16;
  const int rp_1 = ((kb8 + swz8(l7)) & 7) * 16;
  const int rp_2 = ((kb8 + swz8((l7 + 1) & 7)) & 7) * 16;
  const int wpb  = ((s_ckb + swz8(s_c & 7)) & 7) * 16;   // write, half 0

  uint4 ld[5];
  // Unconditional clamped loads: every wave issues exactly 5 (counted-vmcnt needs
  // wave-uniform VMEM counts; the old wave-uniform skip would desync them).
  #define LOADX(ICS)                                                          \
    {                                                                         \
      _Pragma("unroll")                                                       \
      for (int it = 0; it < 5; it++) {                                        \
        int r = it * 2 + s_rb;                                                \
        int h = h0 + r - 1;                                                   \
        int hc = h < 0 ? 0 : (h > 63 ? 63 : h);                               \
        ld[it] = *(const uint4*)(xbase + (size_t)hc * 64 * IN_C + (ICS) * 32);\
      }                                                                       \
    }
  // Halo rows skipped (pre-zeroed once); ds_writes drain to 0 at beta0, so the
  // wave-uniform branch is lgkm-safe.
  #define WRITEX(WP)                                                          \
    {                                                                         \
      _Pragma("unroll")                                                       \
      for (int it = 0; it < 5; it++) {                                        \
        int r = it * 2 + s_rb;                                                \
        int h = h0 + r - 1;                                                   \
        if ((unsigned)h < 64u)                                                \
          *(uint4*)(xsb + r * 8448 + (s_c + 1) * 128 + (WP)) = ld[it];        \
      }                                                                       \
    }
  // 3-tap weight group: 3 glds/thread (24576 B), linear dest, source pre-swizzled.
  #define LOADW_G(ICS, G)                                                     \
    {                                                                         \
      const char* wt = wsw + (size_t)((ICS) * 4 + ot) * WT_TILE_BYTES;        \
      _Pragma("unroll")                                                       \
      for (int it = 0; it < 3; it++) {                                        \
        int off = (((G) * 3 + it) * 512 + tid) * 16;                          \
        __builtin_amdgcn_global_load_lds(                                     \
            (const __attribute__((address_space(1))) void*)(wt + off),        \
            (__attribute__((address_space(3))) void*)(wsb + off), 16, 0, 0);  \
      }                                                                       \
    }

  f32x4 acc[4][8];
  #pragma unroll
  for (int i = 0; i < 4; i++)
    #pragma unroll
    for (int j = 0; j < 8; j++) acc[i][j] = f32x4{0.f, 0.f, 0.f, 0.f};

  // swizzled weight read address (unchanged scheme)
  const int ocr_base = wm * 64 + l15;
  const int swz = ((l15 >> 1) & 7) << 4;
  const int wrd_base = ((ocr_base << 6) + kb8 * 16) ^ swz;

  // per-fn x-tile byte offsets (constant after unroll -> registers)
  int xoff[8];
  #pragma unroll
  for (int fn = 0; fn < 8; fn++) {
    int px = wn * 128 + fn * 16 + l15;
    xoff[fn] = (px >> 6) * 8448 + (px & 63) * 128;
  }

  bf16x8 afA[4], bfA[8], afB[4], bfB[8];
  #define LOADT(T, AF, BF)                                                    \
    {                                                                         \
      _Pragma("unroll")                                                       \
      for (int fm = 0; fm < 4; fm++)                                          \
        AF[fm] = *(const bf16x8*)(wsb + ((T) * 8192 + fm * 1024 + wrd_base)); \
      const int cdx_ = (T) % 3 == 0 ? c0 : ((T) % 3 == 1 ? c1 : c2);          \
      _Pragma("unroll")                                                       \
      for (int fn = 0; fn < 8; fn++)                                          \
        BF[fn] = *(const bf16x8*)(xsb + xoff[fn] + ((T) / 3) * 8448 +         \
                                  ((T) % 3) * 128 + cdx_);                    \
    }
  #define MFMAT(AF, BF)                                                       \
    {                                                                         \
      _Pragma("unroll")                                                       \
      for (int fm = 0; fm < 4; fm++)                                          \
        _Pragma("unroll")                                                     \
        for (int fn = 0; fn < 8; fn++)                                        \
          acc[fm][fn] = __builtin_amdgcn_mfma_f32_16x16x32_bf16(              \
              AF[fm], BF[fn], acc[fm][fn], 0, 0, 0);                          \
    }
  #define GROUP3(T0)                                                          \
    LOADT(T0 + 0, afA, bfA)                                                   \
    LOADT(T0 + 1, afB, bfB)                                                   \
    PRIO1(); MFMAT(afA, bfA); PRIO0(); SGB_MIX()                              \
    LOADT(T0 + 2, afA, bfA)                                                   \
    PRIO1(); MFMAT(afB, bfB); PRIO0(); SGB_MIX()                              \
    PRIO1(); MFMAT(afA, bfA); PRIO0(); SGB_MFMA()

  // ---- prologue: zero halo columns (slots 0,65) + halo rows (edge blocks only)
  {
    uint4 z = {0, 0, 0, 0};
    if (tid < 160) {
      int r = tid >> 4, side = (tid >> 3) & 1, ch = tid & 7;
      *(uint4*)(xsb + r * 8448 + side * 65 * 128 + ch * 16) = z;
    }
    if (h0 == 0)
      for (int i = tid; i < 528; i += 512) ((uint4*)xsb)[i] = z;
    if (h0 == 56)
      for (int i = tid; i < 528; i += 512) ((uint4*)(xsb + 9 * 8448))[i] = z;
  }
  LOADX(0)
  LOADW_G(0, 0)   // W0(0)
  LOADW_G(0, 1)   // W1(0)
  WAITV(0);       // once; loop never drains to 0
  WRITEX(wpb)     // ic-slice 0 -> half 0

  // steady-state per-wave vmcnt ledger (issue order beta2(s-1):W1 | beta0:LX,W2 | beta1:W0'):
  //  beta0: {W0,W1}=6       -> vmcnt(3) completes W0
  //  beta1: {W1,LX,W2}=11   -> vmcnt(8) completes W1
  //  beta2: {LX,W2,W0'}=11  -> vmcnt(3) completes LX+W2 (any LX/W2 intra-order)
  for (int s = 0; s < 16; s++) {
    const int sn = s < 15 ? s + 1 : 15;          // tail: benign clamped reloads keep counts uniform
    const int hh = (s & 1) << 6;                 // ic-half select = XOR 64 on chunk pos
    const int c0 = rp_0 ^ hh, c1 = rp_1 ^ hh, c2 = rp_2 ^ hh;
    const int wp = wpb ^ hh ^ 64;                // write half (s+1)&1

    // beta0: W0(s) ready; xs half s&1 ready (drain prev WRITEX)
    WAITV(3); WAITL(); SBAR();
    LOADX(sn)
    LOADW_G(s, 2)        // W2(s), consumed at beta2
    GROUP3(0)

    // beta1: W1(s) ready
    WAITV(8); SBAR();
    LOADW_G(sn, 0)       // W0(s+1)
    GROUP3(3)

    // beta2: W2(s) + LOADX ready
    WAITV(3); SBAR();
    WRITEX(wp)
    LOADW_G(sn, 1)       // W1(s+1)
    GROUP3(6)
  }
  WAITV(0);   // drain tail glds before LDS dealloc / epilogue

  // epilogue: D row = oc (= kb8*4+j), col = px (= l15)
  #pragma unroll
  for (int fm = 0; fm < 4; fm++) {
    #pragma unroll
    for (int j = 0; j < 4; j++) {
      int oc = oc0 + wm * 64 + fm * 16 + kb8 * 4 + j;
      float dm = dsc[b * OUT_C + oc];
      float* orow = out + ((size_t)b * OUT_C + oc) * NPX + h0 * 64;
      #pragma unroll
      for (int fn = 0; fn < 8; fn++) {
        int px = wn * 128 + fn * 16 + l15;
        orow[px] = acc[fm][fn][j] * dm;
      }
    }
  }
}

extern "C" void kernel_launch(void* const* d_in, const int* in_sizes, int n_in,
                              void* d_out, int out_size, void* d_ws, size_t ws_size,
                              hipStream_t stream) {
  const float* input  = (const float*)d_in[0];
  const float* style  = (const float*)d_in[1];
  const float* weight = (const float*)d_in[2];
  const float* mod_w  = (const float*)d_in[3];
  const float* mod_b  = (const float*)d_in[4];
  float* out = (float*)d_out;

  char* p = (char*)d_ws;
  float* s    = (float*)p;  p += (size_t)BATCH * IN_C * 4;       // 32 KB
  float* dsc  = (float*)p;  p += (size_t)BATCH * OUT_C * 4;      // 32 KB
  float* wsq  = (float*)p;  p += (size_t)OUT_C * IN_C * 4;       // 1 MB
  char*  wsw  = p;          p += (size_t)16 * 4 * WT_TILE_BYTES; // 4.5 MB
  __bf16* xm  = (__bf16*)p;                                      // 64 MB

  style_k<<<BATCH, 512, 0, stream>>>(style, mod_w, mod_b, s);
  wprep_k<<<1024, 256, 0, stream>>>(weight, wsq, wsw);
  demod_k<<<BATCH, 512, 0, stream>>>(s, wsq, dsc);
  modx_k<<<BATCH * 8 * 64, 256, 0, stream>>>(input, s, xm);
  conv_k<<<BATCH * 4 * 8, 512, 0, stream>>>(xm, wsw, dsc, out);
}